// Round 16
// baseline (566.973 us; speedup 1.0000x reference)
//
#include <hip/hip_runtime.h>
#include <hip/hip_bf16.h>
#include <math.h>

#define TOK   8192
#define DDIM  1024
#define HDIM  4096
#define NEXP  8
#define CAP   17408   /* 16384 + 8*128 pad = 136*128 */

typedef __attribute__((ext_vector_type(8))) short  bfrag;
typedef __attribute__((ext_vector_type(4))) float  ffrag;
typedef __attribute__((ext_vector_type(8))) unsigned short us8;

__device__ __forceinline__ unsigned short f2bf(float f) {
  __hip_bfloat16 b = __float2bfloat16(f);     // HW v_cvt, RNE
  return *reinterpret_cast<unsigned short*>(&b);
}
__device__ __forceinline__ float bf2f(unsigned short u) {
  return __uint_as_float((unsigned int)u << 16);
}

__device__ __forceinline__ void gll16(const void* g, void* l) {
  __builtin_amdgcn_global_load_lds(
      (const __attribute__((address_space(1))) unsigned int*)g,
      (__attribute__((address_space(3))) unsigned int*)l,
      16, 0, 0);
}

// 128-aligned exclusive scan of cnt (uniform, 8 entries)
__device__ __forceinline__ void local_scan(const int* __restrict__ cnt, int* offs) {
  int o = 0;
#pragma unroll
  for (int e = 0; e < NEXP; ++e) {
    offs[e] = o;
    o += ((cnt[e] + 127) >> 7) << 7;
  }
  offs[NEXP] = o;
}

// ---- shared transpose tile body (r15-proven: blocked out, 2-round prefetch,
//      LDS dbuf). T = 2*4352 floats of caller's LDS. tile in [0,1024). ----
__device__ __forceinline__ void transpose_tile(const float* __restrict__ in0,
                                               unsigned short* __restrict__ out0,
                                               int R, int C, int tile, float* T) {
  int e = tile >> 7;
  int t = tile & 127;
  int tpr = C >> 8;
  int ty = t / tpr, tx = t % tpr;
  size_t bo = (size_t)e * R * C;
  const float* in = in0 + bo;
  unsigned short* out = out0 + bo;
  int r0 = ty * 128, c0 = tx * 256;

  int tid = threadIdx.x;
  int r4 = (tid >> 4) * 4;
  int c4 = (tid & 15) * 4;
  int oc = tid >> 2;
  int kg = (tid & 3) * 16;

  auto ld = [&](int s, float4* v) {
    int rb = r0 + (s >> 2) * 64;
    int cb = c0 + (s & 3) * 64;
    v[0] = *(const float4*)&in[(size_t)(rb + r4 + 0) * C + cb + c4];
    v[1] = *(const float4*)&in[(size_t)(rb + r4 + 1) * C + cb + c4];
    v[2] = *(const float4*)&in[(size_t)(rb + r4 + 2) * C + cb + c4];
    v[3] = *(const float4*)&in[(size_t)(rb + r4 + 3) * C + cb + c4];
  };

  float4 v[4], nv[4];
  ld(0, v);
#pragma unroll
  for (int s = 0; s < 8; ++s) {
    if (s + 1 < 8) ld(s + 1, nv);
    float* Tb = T + (s & 1) * 4352;
    int rb = r0 + (s >> 2) * 64;
    int cb = c0 + (s & 3) * 64;
    float4 t0 = { v[0].x, v[1].x, v[2].x, v[3].x };
    float4 t1 = { v[0].y, v[1].y, v[2].y, v[3].y };
    float4 t2 = { v[0].z, v[1].z, v[2].z, v[3].z };
    float4 t3 = { v[0].w, v[1].w, v[2].w, v[3].w };
    *(float4*)&Tb[(c4 + 0) * 68 + r4] = t0;
    *(float4*)&Tb[(c4 + 1) * 68 + r4] = t1;
    *(float4*)&Tb[(c4 + 2) * 68 + r4] = t2;
    *(float4*)&Tb[(c4 + 3) * 68 + r4] = t3;
    __syncthreads();
    float4 f0 = *(const float4*)&Tb[oc * 68 + kg + 0];
    float4 f1 = *(const float4*)&Tb[oc * 68 + kg + 4];
    float4 f2 = *(const float4*)&Tb[oc * 68 + kg + 8];
    float4 f3 = *(const float4*)&Tb[oc * 68 + kg + 12];
    us8 a, b;
    a[0] = (short)f2bf(f0.x); a[1] = (short)f2bf(f0.y);
    a[2] = (short)f2bf(f0.z); a[3] = (short)f2bf(f0.w);
    a[4] = (short)f2bf(f1.x); a[5] = (short)f2bf(f1.y);
    a[6] = (short)f2bf(f1.z); a[7] = (short)f2bf(f1.w);
    b[0] = (short)f2bf(f2.x); b[1] = (short)f2bf(f2.y);
    b[2] = (short)f2bf(f2.z); b[3] = (short)f2bf(f2.w);
    b[4] = (short)f2bf(f3.x); b[5] = (short)f2bf(f3.y);
    b[6] = (short)f2bf(f3.z); b[7] = (short)f2bf(f3.w);
    size_t sub = ((size_t)(cb >> 6) * (R >> 6) + (rb >> 6)) * 4096;
    *(us8*)&out[sub + oc * 64 + kg + 0] = a;
    *(us8*)&out[sub + oc * 64 + kg + 8] = b;
    __syncthreads();
    v[0] = nv[0]; v[1] = nv[1]; v[2] = nv[2]; v[3] = nv[3];
  }
}

// ---- prep1: blocks [0,256) gate; blocks [256,1280) W1 transpose ----
__global__ __launch_bounds__(256)
void prep1_kernel(const float* __restrict__ x,  const float* __restrict__ Wg,
                  const float* __restrict__ bg, unsigned short* __restrict__ xb,
                  int* __restrict__ topi, float* __restrict__ topw,
                  int* __restrict__ cnt, int* __restrict__ token_of,
                  const float* __restrict__ W1, unsigned short* __restrict__ w1b) {
  __shared__ __align__(16) float T[2 * 4352];
  int tid = threadIdx.x;

  if (blockIdx.x >= 256) {
    int orig = blockIdx.x - 256;
    int bid = (orig & 7) * 128 + (orig >> 3);   // XCD-chunked over 1024
    transpose_tile(W1, w1b, DDIM, HDIM, bid, T);
    return;
  }

  // ---------------- gate path (r12 gate_v3 logic) ----------------
  int* hist = (int*)T;
  if (tid < NEXP) hist[tid] = 0;
  int gid = blockIdx.x * 256 + tid;
  if (gid < CAP) token_of[gid] = -1;
  __syncthreads();

  int w = tid >> 6, l = tid & 63;
  const float4* wg4 = (const float4*)Wg;
#pragma unroll 1
  for (int ti = 0; ti < 8; ++ti) {
    int t = (blockIdx.x * 4 + w) * 8 + ti;
    const float4* xr = (const float4*)(x + (size_t)t * DDIM);
    float acc[8];
#pragma unroll
    for (int e = 0; e < 8; ++e) acc[e] = 0.f;
#pragma unroll
    for (int gi = 0; gi < 2; ++gi) {
      int f = gi * 128 + 2 * l;
      float4 a0 = xr[f], a1 = xr[f + 1];
      us8 o;
      o[0] = (short)f2bf(a0.x); o[1] = (short)f2bf(a0.y);
      o[2] = (short)f2bf(a0.z); o[3] = (short)f2bf(a0.w);
      o[4] = (short)f2bf(a1.x); o[5] = (short)f2bf(a1.y);
      o[6] = (short)f2bf(a1.z); o[7] = (short)f2bf(a1.w);
      *(us8*)&xb[(size_t)t * DDIM + f * 4] = o;
      float xs[8] = { a0.x, a0.y, a0.z, a0.w, a1.x, a1.y, a1.z, a1.w };
      int dbase = f * 4;
#pragma unroll
      for (int c = 0; c < 8; ++c) {
        float4 w0 = wg4[(dbase + c) * 2 + 0];
        float4 w1 = wg4[(dbase + c) * 2 + 1];
        acc[0] += xs[c] * w0.x; acc[1] += xs[c] * w0.y;
        acc[2] += xs[c] * w0.z; acc[3] += xs[c] * w0.w;
        acc[4] += xs[c] * w1.x; acc[5] += xs[c] * w1.y;
        acc[6] += xs[c] * w1.z; acc[7] += xs[c] * w1.w;
      }
    }
#pragma unroll
    for (int off = 32; off >= 1; off >>= 1)
#pragma unroll
      for (int e = 0; e < 8; ++e) acc[e] += __shfl_down(acc[e], off);
    if (l == 0) {
      float v[8];
#pragma unroll
      for (int e = 0; e < 8; ++e) v[e] = acc[e] + bg[e];
      int i0 = 0;
#pragma unroll
      for (int e = 1; e < 8; ++e) if (v[e] > v[i0]) i0 = e;
      int i1 = -1;
#pragma unroll
      for (int e = 0; e < 8; ++e) if (e != i0 && (i1 < 0 || v[e] > v[i1])) i1 = e;
      float e1 = expf(v[i1] - v[i0]);
      float s = 1.f + e1;
      topi[t * 2 + 0] = i0; topi[t * 2 + 1] = i1;
      topw[t * 2 + 0] = 1.f / s; topw[t * 2 + 1] = e1 / s;
      atomicAdd(&hist[i0], 1);
      atomicAdd(&hist[i1], 1);
    }
  }
  __syncthreads();
  if (tid < NEXP) atomicAdd(&cnt[tid], hist[tid]);
}

// ---------------- assign rows (needs gate complete) ----------------
__global__ __launch_bounds__(256) void assign_kernel(const int* __restrict__ topi,
                                                     const int* __restrict__ cnt,
                                                     int* __restrict__ cursor,
                                                     int* __restrict__ row_of,
                                                     int* __restrict__ token_of) {
  int offs[NEXP + 1];
  local_scan(cnt, offs);
  int id = blockIdx.x * 256 + threadIdx.x;
  int e = topi[id];
  int slot = atomicAdd(&cursor[e], 1);
  int row = offs[e] + slot;
  row_of[id] = row;
  token_of[row] = id >> 1;
}

// ---- union: blocks [0,1024) W2 transpose; [1024,5376) GEMM1 (r12 structure) ----
// GEMM1 doesn't read w2b, so the memory-bound W2 transpose co-runs with the
// compute-bound GEMM1 blocks (complementary pipes) instead of serializing.
__global__ __launch_bounds__(256)
void gemm1_union(const unsigned short* __restrict__ A,
                 const unsigned short* __restrict__ B0,
                 const float* __restrict__ bias0,
                 unsigned short* __restrict__ hout,
                 const int* __restrict__ cnt,
                 const int* __restrict__ token_of,
                 const float* __restrict__ W2, unsigned short* __restrict__ w2b) {
  __shared__ __align__(16) char sm[49152];
  constexpr int N = HDIM, Kfull = DDIM;

  if (blockIdx.x < 1024) {
    int orig = blockIdx.x;
    int bid = (orig & 7) * 128 + (orig >> 3);   // XCD-chunked over 1024
    transpose_tile(W2, w2b, HDIM, DDIM, bid, (float*)sm);
    return;
  }

  int offsets[NEXP + 1];
  local_scan(cnt, offsets);

  // XCD swizzle over the 4352 GEMM blocks (gx=32, gy=136 virtual grid)
  int orig = blockIdx.x - 1024;                 // [0,4352)
  int xcd = orig & 7;
  int vloc = orig >> 3;                          // [0,544)
  int g = vloc / 136;
  int rem = vloc - g * 136;
  int m = rem >> 3;
  int bx = g * 8 + (rem & 7);                    // [0,32)
  int by = xcd * 17 + m;                         // [0,136)

  int row0 = by * 128;
  if (row0 >= offsets[NEXP]) return;
  int e = 0;
  while (row0 >= offsets[e + 1]) ++e;
  const unsigned short* B = B0 + (size_t)e * N * Kfull;
  const float* bias = bias0 + (size_t)e * N;
  int n0 = bx * 128;

  int tid = threadIdx.x;
  int w = tid >> 6, l = tid & 63;
  int lrow = l & 15, kq = l >> 4;
  int wm = w >> 1, wn = w & 1;

  int c2 = (l & 7) ^ (l >> 3);
  int rloc = ((l >> 3) << 1) + (c2 >> 2);
  int ksw = (c2 & 3) * 16;
  int s0 = 2 * w, s1 = 2 * w + 1;

  int gr0 = row0 + s0 * 16 + rloc, gr1 = row0 + s1 * 16 + rloc;
  int t0 = token_of[gr0]; int ar0 = t0 < 0 ? 0 : t0;
  int t1 = token_of[gr1]; int ar1 = t1 < 0 ? 0 : t1;
  const char* srcA0 = (const char*)(A + (size_t)ar0 * Kfull) + ksw;
  const char* srcA1 = (const char*)(A + (size_t)ar1 * Kfull) + ksw;
  auto bsrc = [&](int nloc) -> const char* {
    int n = n0 + nloc;
    return (const char*)B + ((size_t)(n >> 6) * (Kfull >> 6)) * 8192 + (n & 63) * 128 + ksw;
  };
  const char* srcB0 = bsrc(s0 * 16 + rloc);
  const char* srcB1 = bsrc(s1 * 16 + rloc);

  auto stage = [&](int buf, int k0) {
    int kbA = k0 * 2;
    int kbB = (k0 >> 6) * 8192 + (k0 & 63) * 2;
    gll16(srcA0 + kbA, sm + buf * 8192 + s0 * 1024);
    gll16(srcA1 + kbA, sm + buf * 8192 + s1 * 1024);
    gll16(srcB0 + kbB, sm + 24576 + buf * 8192 + s0 * 1024);
    gll16(srcB1 + kbB, sm + 24576 + buf * 8192 + s1 * 1024);
  };

  int offA[4], offB[4];
#pragma unroll
  for (int i = 0; i < 4; ++i) {
    int ra = wm * 64 + i * 16 + lrow;
    offA[i] = (ra >> 1) * 128 + (((((ra & 1) << 2) + kq) ^ ((ra >> 1) & 7)) << 4);
    int rb = wn * 64 + i * 16 + lrow;
    offB[i] = 24576 + (rb >> 1) * 128 + (((((rb & 1) << 2) + kq) ^ ((rb >> 1) & 7)) << 4);
  }

  ffrag acc[4][4];
#pragma unroll
  for (int i = 0; i < 4; ++i)
#pragma unroll
    for (int j = 0; j < 4; ++j) acc[i][j] = (ffrag){0.f, 0.f, 0.f, 0.f};

  auto compute = [&](int buf) {
    int ab = buf * 8192;
    bfrag a[4], b[4];
#pragma unroll
    for (int i = 0; i < 4; ++i) a[i] = *(const bfrag*)(sm + ab + offA[i]);
#pragma unroll
    for (int j = 0; j < 4; ++j) b[j] = *(const bfrag*)(sm + ab + offB[j]);
#pragma unroll
    for (int i = 0; i < 4; ++i)
#pragma unroll
      for (int j = 0; j < 4; ++j)
        acc[i][j] = __builtin_amdgcn_mfma_f32_16x16x32_bf16(a[i], b[j], acc[i][j], 0, 0, 0);
  };

  stage(0, 0); stage(1, 32);
  asm volatile("s_waitcnt vmcnt(4)" ::: "memory");
  __builtin_amdgcn_s_barrier();

  const int nk = Kfull / 32;
  int cur = 0;
  for (int kt = 0; kt < nk; ++kt) {
    int nxt2 = cur + 2; if (nxt2 >= 3) nxt2 -= 3;
    if (kt + 2 < nk) stage(nxt2, (kt + 2) * 32);
    compute(cur);
    if (kt + 1 < nk) {
      if (kt + 2 < nk) { asm volatile("s_waitcnt vmcnt(4)" ::: "memory"); }
      else             { asm volatile("s_waitcnt vmcnt(0)" ::: "memory"); }
    }
    __builtin_amdgcn_s_barrier();
    ++cur; if (cur == 3) cur = 0;
  }

  unsigned short* ht = (unsigned short*)sm;
#pragma unroll
  for (int j = 0; j < 4; ++j) {
    int col = wn * 64 + j * 16 + lrow;
    float bj = bias[n0 + col];
#pragma unroll
    for (int i = 0; i < 4; ++i) {
      int rl = wm * 64 + i * 16 + kq * 4;
#pragma unroll
      for (int r = 0; r < 4; ++r) {
        float v = acc[i][j][r] + bj;
        float z = 1.5957691216f * (v + 0.044715f * v * v * v);
        v = v / (1.0f + __expf(-z));
        ht[(rl + r) * 128 + col] = f2bf(v);
      }
    }
  }
  __syncthreads();
#pragma unroll
  for (int it = 0; it < 8; ++it) {
    int c = it * 256 + tid;
    int row = c >> 4;
    int cc = (c & 15) * 8;
    us8 v = *(const us8*)&ht[row * 128 + cc];
    *(us8*)&hout[(size_t)(row0 + row) * N + n0 + cc] = v;
  }
}

// ---- GEMM2 (r15 KSPLIT structure, unchanged) ----
__global__ __launch_bounds__(256)
void moe_gemm2(const unsigned short* __restrict__ A,
               const unsigned short* __restrict__ B0,
               const float* __restrict__ bias0,
               unsigned short* __restrict__ out,
               const int* __restrict__ cnt) {
  constexpr int N = DDIM, Kfull = HDIM;
  int offsets[NEXP + 1];
  local_scan(cnt, offsets);

  int nwg = gridDim.x * gridDim.y;
  int orig = blockIdx.y * gridDim.x + blockIdx.x;
  int V = nwg >> 3;
  int vid = (orig & 7) * V + (orig >> 3);
  int xcd = vid / V;
  int vloc = vid - xcd * V;
  int P = V / gridDim.x;
  int CW = gridDim.x >= 8 ? 8 : gridDim.x;
  int per = P * CW;
  int g = vloc / per;
  int rem = vloc - g * per;
  int m = rem / CW;
  int bx = g * CW + (rem - m * CW);
  int by = xcd * P + m;

  int kp = bx & 1; bx >>= 1;
  const int Klocal = Kfull >> 1;
  int koff = kp * Klocal;
  out += (size_t)kp * CAP * N;

  int row0 = by * 128;
  if (row0 >= offsets[NEXP]) return;
  int e = 0;
  while (row0 >= offsets[e + 1]) ++e;
  const unsigned short* B = B0 + (size_t)e * N * Kfull;
  const float* bias = bias0 + (size_t)e * N;
  int n0 = bx * 128;

  __shared__ __align__(16) char sm[49152];

  int tid = threadIdx.x;
  int w = tid >> 6, l = tid & 63;
  int lrow = l & 15, kq = l >> 4;
  int wm = w >> 1, wn = w & 1;

  int c2 = (l & 7) ^ (l >> 3);
  int rloc = ((l >> 3) << 1) + (c2 >> 2);
  int ksw = (c2 & 3) * 16;
  int s0 = 2 * w, s1 = 2 * w + 1;

  int gr0 = row0 + s0 * 16 + rloc, gr1 = row0 + s1 * 16 + rloc;
  const char* srcA0 = (const char*)(A + (size_t)gr0 * Kfull + koff) + ksw;
  const char* srcA1 = (const char*)(A + (size_t)gr1 * Kfull + koff) + ksw;
  auto bsrc = [&](int nloc) -> const char* {
    int n = n0 + nloc;
    return (const char*)B + ((size_t)(n >> 6) * (Kfull >> 6) + (koff >> 6)) * 8192
         + (n & 63) * 128 + ksw;
  };
  const char* srcB0 = bsrc(s0 * 16 + rloc);
  const char* srcB1 = bsrc(s1 * 16 + rloc);

  auto stage = [&](int buf, int k0) {
    int kbA = k0 * 2;
    int kbB = (k0 >> 6) * 8192 + (k0 & 63) * 2;
    gll16(srcA0 + kbA, sm + buf * 8192 + s0 * 1024);
    gll16(srcA1 + kbA, sm + buf * 8192 + s1 * 1024);
    gll16(srcB0 + kbB, sm + 24576 + buf * 8192 + s0 * 1024);
    gll16(srcB1 + kbB, sm + 24576 + buf * 8192 + s1 * 1024);
  };

  int offA[4], offB[4];
#pragma unroll
  for (int i = 0; i < 4; ++i) {
    int ra = wm * 64 + i * 16 + lrow;
    offA[i] = (ra >> 1) * 128 + (((((ra & 1) << 2) + kq) ^ ((ra >> 1) & 7)) << 4);
    int rb = wn * 64 + i * 16 + lrow;
    offB[i] = 24576 + (rb >> 1) * 128 + (((((rb & 1) << 2) + kq) ^ ((rb >> 1) & 7)) << 4);
  }

  ffrag acc[4][4];
#pragma unroll
  for (int i = 0; i < 4; ++i)
#pragma unroll
    for (int j = 0; j < 4; ++j) acc[i][j] = (ffrag){0.f, 0.f, 0.f, 0.f};

  auto compute = [&](int buf) {
    int ab = buf * 8192;
    bfrag a[4], b[4];
#pragma unroll
    for (int i = 0; i < 4; ++i) a[i] = *(const bfrag*)(sm + ab + offA[i]);
#pragma unroll
    for (int j = 0; j < 4; ++j) b[j] = *(const bfrag*)(sm + ab + offB[j]);
#pragma unroll
    for (int i = 0; i < 4; ++i)
#pragma unroll
      for (int j = 0; j < 4; ++j)
        acc[i][j] = __builtin_amdgcn_mfma_f32_16x16x32_bf16(a[i], b[j], acc[i][j], 0, 0, 0);
  };

  stage(0, 0); stage(1, 32);
  asm volatile("s_waitcnt vmcnt(4)" ::: "memory");
  __builtin_amdgcn_s_barrier();

  const int nk = Klocal / 32;
  int cur = 0;
  for (int kt = 0; kt < nk; ++kt) {
    int nxt2 = cur + 2; if (nxt2 >= 3) nxt2 -= 3;
    if (kt + 2 < nk) stage(nxt2, (kt + 2) * 32);
    compute(cur);
    if (kt + 1 < nk) {
      if (kt + 2 < nk) { asm volatile("s_waitcnt vmcnt(4)" ::: "memory"); }
      else             { asm volatile("s_waitcnt vmcnt(0)" ::: "memory"); }
    }
    __builtin_amdgcn_s_barrier();
    ++cur; if (cur == 3) cur = 0;
  }

  unsigned short* ht = (unsigned short*)sm;
#pragma unroll
  for (int j = 0; j < 4; ++j) {
    int col = wn * 64 + j * 16 + lrow;
    float bj = (kp == 0) ? bias[n0 + col] : 0.0f;
#pragma unroll
    for (int i = 0; i < 4; ++i) {
      int rl = wm * 64 + i * 16 + kq * 4;
#pragma unroll
      for (int r = 0; r < 4; ++r) {
        ht[(rl + r) * 128 + col] = f2bf(acc[i][j][r] + bj);
      }
    }
  }
  __syncthreads();
#pragma unroll
  for (int it = 0; it < 8; ++it) {
    int c = it * 256 + tid;
    int row = c >> 4;
    int cc = (c & 15) * 8;
    us8 v = *(const us8*)&ht[row * 128 + cc];
    *(us8*)&out[(size_t)(row0 + row) * N + n0 + cc] = v;
  }
}

// -------- combine: sum two bf16 K-partials, weight, fp32 out --------
__global__ __launch_bounds__(256) void combine_kernel(const unsigned short* __restrict__ y,
                                                      const int* __restrict__ row_of,
                                                      const float* __restrict__ topw,
                                                      float* __restrict__ out) {
  int t = blockIdx.x;
  int r0 = row_of[t * 2 + 0], r1 = row_of[t * 2 + 1];
  float w0 = topw[t * 2 + 0], w1 = topw[t * 2 + 1];
  const size_t P1 = (size_t)CAP * DDIM;
  const ushort4* a0 = (const ushort4*)(y + (size_t)r0 * DDIM);
  const ushort4* a1 = (const ushort4*)(y + P1 + (size_t)r0 * DDIM);
  const ushort4* b0 = (const ushort4*)(y + (size_t)r1 * DDIM);
  const ushort4* b1 = (const ushort4*)(y + P1 + (size_t)r1 * DDIM);
  float4* o = (float4*)(out + (size_t)t * DDIM);
  int i = threadIdx.x;
  ushort4 pa0 = a0[i], pa1 = a1[i], pb0 = b0[i], pb1 = b1[i];
  float4 r = {
    w0 * (bf2f(pa0.x) + bf2f(pa1.x)) + w1 * (bf2f(pb0.x) + bf2f(pb1.x)),
    w0 * (bf2f(pa0.y) + bf2f(pa1.y)) + w1 * (bf2f(pb0.y) + bf2f(pb1.y)),
    w0 * (bf2f(pa0.z) + bf2f(pa1.z)) + w1 * (bf2f(pb0.z) + bf2f(pb1.z)),
    w0 * (bf2f(pa0.w) + bf2f(pa1.w)) + w1 * (bf2f(pb0.w) + bf2f(pb1.w))
  };
  o[i] = r;
}

extern "C" void kernel_launch(void* const* d_in, const int* in_sizes, int n_in,
                              void* d_out, int out_size, void* d_ws, size_t ws_size,
                              hipStream_t stream) {
  const float* x  = (const float*)d_in[0];
  const float* Wg = (const float*)d_in[1];
  const float* bg = (const float*)d_in[2];
  const float* W1 = (const float*)d_in[3];
  const float* b1 = (const float*)d_in[4];
  const float* W2 = (const float*)d_in[5];
  const float* b2 = (const float*)d_in[6];
  float* out = (float*)d_out;

  size_t off = 0;
  char* base = (char*)d_ws;
  auto alloc = [&](size_t bytes) -> void* {
    void* p = base + off;
    off += (bytes + 255) & ~(size_t)255;
    return p;
  };
  unsigned short* xb  = (unsigned short*)alloc((size_t)TOK * DDIM * 2);
  unsigned short* w1b = (unsigned short*)alloc((size_t)NEXP * HDIM * DDIM * 2);
  unsigned short* w2b = (unsigned short*)alloc((size_t)NEXP * DDIM * HDIM * 2);
  unsigned short* h   = (unsigned short*)alloc((size_t)CAP * HDIM * 2);
  unsigned short* y   = (unsigned short*)alloc((size_t)2 * CAP * DDIM * 2);
  int*   topi     = (int*)alloc((size_t)TOK * 2 * 4);
  float* topw     = (float*)alloc((size_t)TOK * 2 * 4);
  int*   row_of   = (int*)alloc((size_t)TOK * 2 * 4);
  int*   token_of = (int*)alloc((size_t)CAP * 4);
  int*   cntcur   = (int*)alloc(64);      // cnt = [0..7], cursor = [8..15]
  if (off > ws_size) return;

  int* cnt = cntcur;
  int* cursor = cntcur + 8;

  hipMemsetAsync(cntcur, 0, 64, stream);

  prep1_kernel<<<1280, 256, 0, stream>>>(x, Wg, bg, xb, topi, topw, cnt, token_of,
                                         W1, w1b);
  assign_kernel<<<(TOK * 2) / 256, 256, 0, stream>>>(topi, cnt, cursor,
                                                     row_of, token_of);

  gemm1_union<<<1024 + 4352, 256, 0, stream>>>(xb, w1b, b1, h, cnt, token_of,
                                               W2, w2b);
  moe_gemm2<<<dim3(16, CAP / 128), 256, 0, stream>>>(h, w2b, b2, y, cnt);

  combine_kernel<<<TOK, 256, 0, stream>>>(y, row_of, topw, out);
}

// Round 17
// 533.195 us; speedup vs baseline: 1.0634x; 1.0634x over previous
//
#include <hip/hip_runtime.h>
#include <hip/hip_bf16.h>
#include <math.h>

#define TOK   8192
#define DDIM  1024
#define HDIM  4096
#define NEXP  8
#define CAP   17408   /* 16384 + 8*128 pad = 136*128 */

typedef __attribute__((ext_vector_type(8))) short  bfrag;
typedef __attribute__((ext_vector_type(4))) float  ffrag;
typedef __attribute__((ext_vector_type(8))) unsigned short us8;

__device__ __forceinline__ unsigned short f2bf(float f) {
  __hip_bfloat16 b = __float2bfloat16(f);     // HW v_cvt, RNE
  return *reinterpret_cast<unsigned short*>(&b);
}
__device__ __forceinline__ float bf2f(unsigned short u) {
  return __uint_as_float((unsigned int)u << 16);
}

__device__ __forceinline__ void gll16(const void* g, void* l) {
  __builtin_amdgcn_global_load_lds(
      (const __attribute__((address_space(1))) unsigned int*)g,
      (__attribute__((address_space(3))) unsigned int*)l,
      16, 0, 0);
}

// 128-aligned exclusive scan of cnt (uniform, 8 entries)
__device__ __forceinline__ void local_scan(const int* __restrict__ cnt, int* offs) {
  int o = 0;
#pragma unroll
  for (int e = 0; e < NEXP; ++e) {
    offs[e] = o;
    o += ((cnt[e] + 127) >> 7) << 7;
  }
  offs[NEXP] = o;
}

// ---- fused prep: blocks [0,256) gate; blocks [256,2304) weight transpose ----
__global__ __launch_bounds__(256)
void prep_kernel(const float* __restrict__ x,  const float* __restrict__ Wg,
                 const float* __restrict__ bg, unsigned short* __restrict__ xb,
                 int* __restrict__ topi, float* __restrict__ topw,
                 int* __restrict__ cnt, int* __restrict__ token_of,
                 const float* __restrict__ W1, unsigned short* __restrict__ w1b,
                 const float* __restrict__ W2, unsigned short* __restrict__ w2b) {
  __shared__ __align__(16) float T[2 * 4352];   // transpose dbuf; gate aliases hist
  int tid = threadIdx.x;

  if (blockIdx.x < 256) {
    // ---------------- gate path ----------------
    int* hist = (int*)T;
    if (tid < NEXP) hist[tid] = 0;
    int gid = blockIdx.x * 256 + tid;
    if (gid < CAP) token_of[gid] = -1;
    __syncthreads();

    int w = tid >> 6, l = tid & 63;
    const float4* wg4 = (const float4*)Wg;
#pragma unroll 1
    for (int ti = 0; ti < 8; ++ti) {
      int t = (blockIdx.x * 4 + w) * 8 + ti;
      const float4* xr = (const float4*)(x + (size_t)t * DDIM);
      float acc[8];
#pragma unroll
      for (int e = 0; e < 8; ++e) acc[e] = 0.f;
#pragma unroll
      for (int gi = 0; gi < 2; ++gi) {
        int f = gi * 128 + 2 * l;
        float4 a0 = xr[f], a1 = xr[f + 1];
        us8 o;
        o[0] = (short)f2bf(a0.x); o[1] = (short)f2bf(a0.y);
        o[2] = (short)f2bf(a0.z); o[3] = (short)f2bf(a0.w);
        o[4] = (short)f2bf(a1.x); o[5] = (short)f2bf(a1.y);
        o[6] = (short)f2bf(a1.z); o[7] = (short)f2bf(a1.w);
        *(us8*)&xb[(size_t)t * DDIM + f * 4] = o;
        float xs[8] = { a0.x, a0.y, a0.z, a0.w, a1.x, a1.y, a1.z, a1.w };
        int dbase = f * 4;
#pragma unroll
        for (int c = 0; c < 8; ++c) {
          float4 w0 = wg4[(dbase + c) * 2 + 0];
          float4 w1 = wg4[(dbase + c) * 2 + 1];
          acc[0] += xs[c] * w0.x; acc[1] += xs[c] * w0.y;
          acc[2] += xs[c] * w0.z; acc[3] += xs[c] * w0.w;
          acc[4] += xs[c] * w1.x; acc[5] += xs[c] * w1.y;
          acc[6] += xs[c] * w1.z; acc[7] += xs[c] * w1.w;
        }
      }
#pragma unroll
      for (int off = 32; off >= 1; off >>= 1)
#pragma unroll
        for (int e = 0; e < 8; ++e) acc[e] += __shfl_down(acc[e], off);
      if (l == 0) {
        float v[8];
#pragma unroll
        for (int e = 0; e < 8; ++e) v[e] = acc[e] + bg[e];
        int i0 = 0;
#pragma unroll
        for (int e = 1; e < 8; ++e) if (v[e] > v[i0]) i0 = e;
        int i1 = -1;
#pragma unroll
        for (int e = 0; e < 8; ++e) if (e != i0 && (i1 < 0 || v[e] > v[i1])) i1 = e;
        float e1 = expf(v[i1] - v[i0]);
        float s = 1.f + e1;
        topi[t * 2 + 0] = i0; topi[t * 2 + 1] = i1;
        topw[t * 2 + 0] = 1.f / s; topw[t * 2 + 1] = e1 / s;
        atomicAdd(&hist[i0], 1);
        atomicAdd(&hist[i1], 1);
      }
    }
    __syncthreads();
    if (tid < NEXP) atomicAdd(&cnt[tid], hist[tid]);
    return;
  }

  // ---------------- transpose path ----------------
  int orig = blockIdx.x - 256;
  int bid = (orig & 7) * 256 + (orig >> 3);    // XCD-chunked, bijective
  const float* in; unsigned short* out; int R, C, tile;
  if (bid < 1024) { in = W1; out = w1b; R = DDIM; C = HDIM; tile = bid; }
  else            { in = W2; out = w2b; R = HDIM; C = DDIM; tile = bid - 1024; }
  int e = tile >> 7;
  int t = tile & 127;
  int tpr = C >> 8;
  int ty = t / tpr, tx = t % tpr;
  size_t bo = (size_t)e * R * C;
  in += bo; out += bo;
  int r0 = ty * 128, c0 = tx * 256;

  int r4 = (tid >> 4) * 4;
  int c4 = (tid & 15) * 4;
  int oc = tid >> 2;
  int kg = (tid & 3) * 16;

  auto ld = [&](int s, float4* v) {
    int rb = r0 + (s >> 2) * 64;
    int cb = c0 + (s & 3) * 64;
    v[0] = *(const float4*)&in[(size_t)(rb + r4 + 0) * C + cb + c4];
    v[1] = *(const float4*)&in[(size_t)(rb + r4 + 1) * C + cb + c4];
    v[2] = *(const float4*)&in[(size_t)(rb + r4 + 2) * C + cb + c4];
    v[3] = *(const float4*)&in[(size_t)(rb + r4 + 3) * C + cb + c4];
  };

  float4 v[4], nv[4];
  ld(0, v);
#pragma unroll
  for (int s = 0; s < 8; ++s) {
    if (s + 1 < 8) ld(s + 1, nv);
    float* Tb = T + (s & 1) * 4352;
    int rb = r0 + (s >> 2) * 64;
    int cb = c0 + (s & 3) * 64;
    float4 t0 = { v[0].x, v[1].x, v[2].x, v[3].x };
    float4 t1 = { v[0].y, v[1].y, v[2].y, v[3].y };
    float4 t2 = { v[0].z, v[1].z, v[2].z, v[3].z };
    float4 t3 = { v[0].w, v[1].w, v[2].w, v[3].w };
    *(float4*)&Tb[(c4 + 0) * 68 + r4] = t0;
    *(float4*)&Tb[(c4 + 1) * 68 + r4] = t1;
    *(float4*)&Tb[(c4 + 2) * 68 + r4] = t2;
    *(float4*)&Tb[(c4 + 3) * 68 + r4] = t3;
    __syncthreads();
    float4 f0 = *(const float4*)&Tb[oc * 68 + kg + 0];
    float4 f1 = *(const float4*)&Tb[oc * 68 + kg + 4];
    float4 f2 = *(const float4*)&Tb[oc * 68 + kg + 8];
    float4 f3 = *(const float4*)&Tb[oc * 68 + kg + 12];
    us8 a, b;
    a[0] = (short)f2bf(f0.x); a[1] = (short)f2bf(f0.y);
    a[2] = (short)f2bf(f0.z); a[3] = (short)f2bf(f0.w);
    a[4] = (short)f2bf(f1.x); a[5] = (short)f2bf(f1.y);
    a[6] = (short)f2bf(f1.z); a[7] = (short)f2bf(f1.w);
    b[0] = (short)f2bf(f2.x); b[1] = (short)f2bf(f2.y);
    b[2] = (short)f2bf(f2.z); b[3] = (short)f2bf(f2.w);
    b[4] = (short)f2bf(f3.x); b[5] = (short)f2bf(f3.y);
    b[6] = (short)f2bf(f3.z); b[7] = (short)f2bf(f3.w);
    size_t sub = ((size_t)(cb >> 6) * (R >> 6) + (rb >> 6)) * 4096;
    *(us8*)&out[sub + oc * 64 + kg + 0] = a;
    *(us8*)&out[sub + oc * 64 + kg + 8] = b;
    v[0] = nv[0]; v[1] = nv[1]; v[2] = nv[2]; v[3] = nv[3];
  }
}

// ---------------- assign rows (needs gate complete) ----------------
__global__ __launch_bounds__(256) void assign_kernel(const int* __restrict__ topi,
                                                     const int* __restrict__ cnt,
                                                     int* __restrict__ cursor,
                                                     int* __restrict__ row_of,
                                                     int* __restrict__ token_of) {
  int offs[NEXP + 1];
  local_scan(cnt, offs);
  int id = blockIdx.x * 256 + threadIdx.x;
  int e = topi[id];
  int slot = atomicAdd(&cursor[e], 1);
  int row = offs[e] + slot;
  row_of[id] = row;
  token_of[row] = id >> 1;
}

// ---- grouped GEMM (r12 structure): 128^2, 3-buf counted-vmcnt, blocked B ----
// KSPLIT: grid (16,136); bx LSB = K-half; partials to out + kp*CAP*N (bias in
// half 0 only). Inner loop/LDS/swizzle identical to the proven r12 kernel.
template<bool INDIRECT, bool GELU, bool KSPLIT>
__global__ __launch_bounds__(256)
void moe_gemm(const unsigned short* __restrict__ A,
              const unsigned short* __restrict__ B0,
              const float* __restrict__ bias0,
              unsigned short* __restrict__ out,
              int N, int Kfull,
              const int* __restrict__ cnt,
              const int* __restrict__ token_of) {
  int offsets[NEXP + 1];
  local_scan(cnt, offsets);

  int nwg = gridDim.x * gridDim.y;
  int orig = blockIdx.y * gridDim.x + blockIdx.x;
  int V = nwg >> 3;
  int vid = (orig & 7) * V + (orig >> 3);
  int xcd = vid / V;
  int vloc = vid - xcd * V;
  int P = V / gridDim.x;
  int CW = gridDim.x >= 8 ? 8 : gridDim.x;
  int per = P * CW;
  int g = vloc / per;
  int rem = vloc - g * per;
  int m = rem / CW;
  int bx = g * CW + (rem - m * CW);
  int by = xcd * P + m;

  int kp = 0, koff = 0, Klocal = Kfull;
  if (KSPLIT) {
    kp = bx & 1; bx >>= 1;
    Klocal = Kfull >> 1;
    koff = kp * Klocal;
    out += (size_t)kp * CAP * N;
  }

  int row0 = by * 128;
  if (row0 >= offsets[NEXP]) return;
  int e = 0;
  while (row0 >= offsets[e + 1]) ++e;
  const unsigned short* B = B0 + (size_t)e * N * Kfull;
  const float* bias = bias0 + (size_t)e * N;
  int n0 = bx * 128;

  __shared__ __align__(16) char sm[49152];

  int tid = threadIdx.x;
  int w = tid >> 6, l = tid & 63;
  int lrow = l & 15, kq = l >> 4;
  int wm = w >> 1, wn = w & 1;

  int c2 = (l & 7) ^ (l >> 3);
  int rloc = ((l >> 3) << 1) + (c2 >> 2);
  int ksw = (c2 & 3) * 16;
  int s0 = 2 * w, s1 = 2 * w + 1;

  int gr0 = row0 + s0 * 16 + rloc, gr1 = row0 + s1 * 16 + rloc;
  int ar0, ar1;
  if (INDIRECT) {
    int t0 = token_of[gr0]; ar0 = t0 < 0 ? 0 : t0;
    int t1 = token_of[gr1]; ar1 = t1 < 0 ? 0 : t1;
  } else { ar0 = gr0; ar1 = gr1; }
  const char* srcA0 = (const char*)(A + (size_t)ar0 * Kfull + koff) + ksw;
  const char* srcA1 = (const char*)(A + (size_t)ar1 * Kfull + koff) + ksw;
  auto bsrc = [&](int nloc) -> const char* {
    int n = n0 + nloc;
    return (const char*)B + ((size_t)(n >> 6) * (Kfull >> 6) + (koff >> 6)) * 8192
         + (n & 63) * 128 + ksw;
  };
  const char* srcB0 = bsrc(s0 * 16 + rloc);
  const char* srcB1 = bsrc(s1 * 16 + rloc);

  auto stage = [&](int buf, int k0) {        // k0 relative to koff, mult of 32
    int kbA = k0 * 2;
    int kbB = (k0 >> 6) * 8192 + (k0 & 63) * 2;
    gll16(srcA0 + kbA, sm + buf * 8192 + s0 * 1024);
    gll16(srcA1 + kbA, sm + buf * 8192 + s1 * 1024);
    gll16(srcB0 + kbB, sm + 24576 + buf * 8192 + s0 * 1024);
    gll16(srcB1 + kbB, sm + 24576 + buf * 8192 + s1 * 1024);
  };

  int offA[4], offB[4];
#pragma unroll
  for (int i = 0; i < 4; ++i) {
    int ra = wm * 64 + i * 16 + lrow;
    offA[i] = (ra >> 1) * 128 + (((((ra & 1) << 2) + kq) ^ ((ra >> 1) & 7)) << 4);
    int rb = wn * 64 + i * 16 + lrow;
    offB[i] = 24576 + (rb >> 1) * 128 + (((((rb & 1) << 2) + kq) ^ ((rb >> 1) & 7)) << 4);
  }

  ffrag acc[4][4];
#pragma unroll
  for (int i = 0; i < 4; ++i)
#pragma unroll
    for (int j = 0; j < 4; ++j) acc[i][j] = (ffrag){0.f, 0.f, 0.f, 0.f};

  auto compute = [&](int buf) {
    int ab = buf * 8192;
    bfrag a[4], b[4];
#pragma unroll
    for (int i = 0; i < 4; ++i) a[i] = *(const bfrag*)(sm + ab + offA[i]);
#pragma unroll
    for (int j = 0; j < 4; ++j) b[j] = *(const bfrag*)(sm + ab + offB[j]);
#pragma unroll
    for (int i = 0; i < 4; ++i)
#pragma unroll
      for (int j = 0; j < 4; ++j)
        acc[i][j] = __builtin_amdgcn_mfma_f32_16x16x32_bf16(a[i], b[j], acc[i][j], 0, 0, 0);
  };

  stage(0, 0); stage(1, 32);
  asm volatile("s_waitcnt vmcnt(4)" ::: "memory");
  __builtin_amdgcn_s_barrier();

  int nk = Klocal / 32;
  int cur = 0;
  for (int kt = 0; kt < nk; ++kt) {
    int nxt2 = cur + 2; if (nxt2 >= 3) nxt2 -= 3;
    if (kt + 2 < nk) stage(nxt2, (kt + 2) * 32);
    compute(cur);
    if (kt + 1 < nk) {
      if (kt + 2 < nk) { asm volatile("s_waitcnt vmcnt(4)" ::: "memory"); }
      else             { asm volatile("s_waitcnt vmcnt(0)" ::: "memory"); }
    }
    __builtin_amdgcn_s_barrier();
    ++cur; if (cur == 3) cur = 0;
  }

  unsigned short* ht = (unsigned short*)sm;
#pragma unroll
  for (int j = 0; j < 4; ++j) {
    int col = wn * 64 + j * 16 + lrow;
    float bj = (!KSPLIT || kp == 0) ? bias[n0 + col] : 0.0f;
#pragma unroll
    for (int i = 0; i < 4; ++i) {
      int rl = wm * 64 + i * 16 + kq * 4;
#pragma unroll
      for (int r = 0; r < 4; ++r) {
        float v = acc[i][j][r] + bj;
        if (GELU) {
          float z = 1.5957691216f * (v + 0.044715f * v * v * v);
          v = v / (1.0f + __expf(-z));
        }
        ht[(rl + r) * 128 + col] = f2bf(v);
      }
    }
  }
  __syncthreads();
#pragma unroll
  for (int it = 0; it < 8; ++it) {
    int c = it * 256 + tid;
    int row = c >> 4;
    int cc = (c & 15) * 8;
    us8 v = *(const us8*)&ht[row * 128 + cc];
    *(us8*)&out[(size_t)(row0 + row) * N + n0 + cc] = v;
  }
}

// -------- combine: sum two bf16 K-partials, weight, fp32 out --------
__global__ __launch_bounds__(256) void combine_kernel(const unsigned short* __restrict__ y,
                                                      const int* __restrict__ row_of,
                                                      const float* __restrict__ topw,
                                                      float* __restrict__ out) {
  int t = blockIdx.x;
  int r0 = row_of[t * 2 + 0], r1 = row_of[t * 2 + 1];
  float w0 = topw[t * 2 + 0], w1 = topw[t * 2 + 1];
  const size_t P1 = (size_t)CAP * DDIM;
  const ushort4* a0 = (const ushort4*)(y + (size_t)r0 * DDIM);
  const ushort4* a1 = (const ushort4*)(y + P1 + (size_t)r0 * DDIM);
  const ushort4* b0 = (const ushort4*)(y + (size_t)r1 * DDIM);
  const ushort4* b1 = (const ushort4*)(y + P1 + (size_t)r1 * DDIM);
  float4* o = (float4*)(out + (size_t)t * DDIM);
  int i = threadIdx.x;
  ushort4 pa0 = a0[i], pa1 = a1[i], pb0 = b0[i], pb1 = b1[i];
  float4 r = {
    w0 * (bf2f(pa0.x) + bf2f(pa1.x)) + w1 * (bf2f(pb0.x) + bf2f(pb1.x)),
    w0 * (bf2f(pa0.y) + bf2f(pa1.y)) + w1 * (bf2f(pb0.y) + bf2f(pb1.y)),
    w0 * (bf2f(pa0.z) + bf2f(pa1.z)) + w1 * (bf2f(pb0.z) + bf2f(pb1.z)),
    w0 * (bf2f(pa0.w) + bf2f(pa1.w)) + w1 * (bf2f(pb0.w) + bf2f(pb1.w))
  };
  o[i] = r;
}

extern "C" void kernel_launch(void* const* d_in, const int* in_sizes, int n_in,
                              void* d_out, int out_size, void* d_ws, size_t ws_size,
                              hipStream_t stream) {
  const float* x  = (const float*)d_in[0];
  const float* Wg = (const float*)d_in[1];
  const float* bg = (const float*)d_in[2];
  const float* W1 = (const float*)d_in[3];
  const float* b1 = (const float*)d_in[4];
  const float* W2 = (const float*)d_in[5];
  const float* b2 = (const float*)d_in[6];
  float* out = (float*)d_out;

  size_t off = 0;
  char* base = (char*)d_ws;
  auto alloc = [&](size_t bytes) -> void* {
    void* p = base + off;
    off += (bytes + 255) & ~(size_t)255;
    return p;
  };
  unsigned short* xb  = (unsigned short*)alloc((size_t)TOK * DDIM * 2);
  unsigned short* w1b = (unsigned short*)alloc((size_t)NEXP * HDIM * DDIM * 2);
  unsigned short* w2b = (unsigned short*)alloc((size_t)NEXP * DDIM * HDIM * 2);
  unsigned short* h   = (unsigned short*)alloc((size_t)CAP * HDIM * 2);
  unsigned short* y   = (unsigned short*)alloc((size_t)2 * CAP * DDIM * 2);
  int*   topi     = (int*)alloc((size_t)TOK * 2 * 4);
  float* topw     = (float*)alloc((size_t)TOK * 2 * 4);
  int*   row_of   = (int*)alloc((size_t)TOK * 2 * 4);
  int*   token_of = (int*)alloc((size_t)CAP * 4);
  int*   cntcur   = (int*)alloc(64);      // cnt = [0..7], cursor = [8..15]
  if (off > ws_size) return;

  int* cnt = cntcur;
  int* cursor = cntcur + 8;

  hipMemsetAsync(cntcur, 0, 64, stream);

  prep_kernel<<<2304, 256, 0, stream>>>(x, Wg, bg, xb, topi, topw, cnt, token_of,
                                        W1, w1b, W2, w2b);
  assign_kernel<<<(TOK * 2) / 256, 256, 0, stream>>>(topi, cnt, cursor,
                                                     row_of, token_of);

  moe_gemm<true, true, false><<<dim3(HDIM / 128, CAP / 128), 256, 0, stream>>>(
      xb, w1b, b1, h, HDIM, DDIM, cnt, token_of);
  moe_gemm<false, false, true><<<dim3(16, CAP / 128), 256, 0, stream>>>(
      h, w2b, b2, y, DDIM, HDIM, cnt, token_of);

  combine_kernel<<<TOK, 256, 0, stream>>>(y, row_of, topw, out);
}